// Round 4
// baseline (190.010 us; speedup 1.0000x reference)
//
#include <hip/hip_runtime.h>
#include <math.h>

typedef __attribute__((ext_vector_type(8))) short bf16x8;
typedef __attribute__((ext_vector_type(4))) float f32x4;
typedef __attribute__((ext_vector_type(4))) unsigned short u16x4;

#define B_    2
#define T_    2048
#define DIM_  1024
#define H_    16
#define KV_   4
#define HD_   64

static __device__ __forceinline__ unsigned short f2bf(float f) {
    union { float f; unsigned int u; } v; v.f = f;
    unsigned int r = v.u + 0x7fff + ((v.u >> 16) & 1);   // RNE
    return (unsigned short)(r >> 16);
}

static __device__ __forceinline__ void gload16(const void* g, void* l) {
    __builtin_amdgcn_global_load_lds(
        (const __attribute__((address_space(1))) unsigned int*)g,
        (__attribute__((address_space(3))) unsigned int*)l, 16, 0, 0);
}

// Workspace (unsigned short elements):
//   xb   bf16 [4096][1024]          off 0
//   Wt   bf16 [1536][1024]          off 4194304   (Wq^T | Wk^T | Wv^T rows)
//   Wot  bf16 [1024][1024]          off 5767168
//   Q    bf16 [B][H][T][64]         off 6815744   (row-major)
//   K    bf16 [B][KV][T][64]        off 11010048  (XOR-swizzled rows: 2d ^ ((t&7)<<4))
//   Vt   bf16 [B][KV][64][T]        off 12058624  (XOR-swizzled: 2t ^ ((d&7)<<4))
//   attnb bf16 [B][T][DIM]          off 13107200
#define XB_OFF   0u
#define WT_OFF   4194304u
#define WOT_OFF  5767168u
#define QB_OFF   6815744u
#define KB_OFF   11010048u
#define VTB_OFF  12058624u
#define AB_OFF   13107200u

// ---------------------------------------------------------------------------
// Pre-pass: f32 -> bf16 convert (8 elems/thread)
// ---------------------------------------------------------------------------
__global__ __launch_bounds__(256) void cvt_kernel(
    const float* __restrict__ in, unsigned short* __restrict__ out)
{
    const size_t i = ((size_t)blockIdx.x * 256 + threadIdx.x) * 8;
    float4 a = *(const float4*)&in[i];
    float4 b = *(const float4*)&in[i + 4];
    unsigned short u[8] = {f2bf(a.x), f2bf(a.y), f2bf(a.z), f2bf(a.w),
                           f2bf(b.x), f2bf(b.y), f2bf(b.z), f2bf(b.w)};
    *(bf16x8*)&out[i] = *(bf16x8*)u;
}

// ---------------------------------------------------------------------------
// Pre-pass: W f32 [1024][N] -> Wt bf16 [N][1024]  (64x64 LDS tile transpose)
// ---------------------------------------------------------------------------
__global__ __launch_bounds__(256) void wtrans_kernel(
    const float* __restrict__ W, unsigned short* __restrict__ Wt, int N)
{
    __shared__ float Ts[64][65];
    const int n0 = blockIdx.x * 64, k0 = blockIdx.y * 64;
    const int tid = threadIdx.x;
    const int r = tid >> 4, c4 = (tid & 15) * 4;
    #pragma unroll
    for (int i = 0; i < 4; ++i) {
        float4 v = *(const float4*)&W[(size_t)(k0 + r + 16 * i) * N + n0 + c4];
        Ts[r + 16 * i][c4 + 0] = v.x; Ts[r + 16 * i][c4 + 1] = v.y;
        Ts[r + 16 * i][c4 + 2] = v.z; Ts[r + 16 * i][c4 + 3] = v.w;
    }
    __syncthreads();
    const int rn = tid >> 3, ck = (tid & 7) * 8;
    #pragma unroll
    for (int i = 0; i < 2; ++i) {
        int n = rn + 32 * i;
        unsigned short u[8];
        #pragma unroll
        for (int e = 0; e < 8; ++e) u[e] = f2bf(Ts[ck + e][n]);
        *(bf16x8*)&Wt[(size_t)(n0 + n) * 1024 + k0 + ck] = *(bf16x8*)u;
    }
}

// ---------------------------------------------------------------------------
// Kernel 1: QKV bf16 MFMA GEMM + RoPE epilogue.
// C[4096][1536] = xb @ Wt^T. 128x128 tile, BK=64, 4 waves of 64x64.
// K and Vt outputs are stored XOR-swizzled (see workspace comments) so the
// attention kernel can stage them with linear global_load_lds.
// ---------------------------------------------------------------------------
__global__ __launch_bounds__(256) void qkv_mfma_kernel(
    const unsigned short* __restrict__ xb, const unsigned short* __restrict__ Wt,
    const float* __restrict__ sinp, const float* __restrict__ cosp,
    unsigned short* __restrict__ Qw, unsigned short* __restrict__ Kw,
    unsigned short* __restrict__ Vtw)
{
    __shared__ __align__(16) unsigned char As[16384];   // [128 m][128B], XOR-swizzled
    __shared__ __align__(16) unsigned char Bs[16384];   // [128 n][128B]

    const int tid = threadIdx.x, lane = tid & 63, w = tid >> 6;
    const int lr = lane & 15, lg = lane >> 4;
    const int wm = w >> 1, wn = w & 1;
    const int bn = blockIdx.x, bm = blockIdx.y;
    const int m0 = bm * 128, n0 = bn * 128;

    const int chunkR = lane >> 3;                    // row within 8-row chunk
    const int srcOff = 8 * ((lane & 7) ^ chunkR);    // inverse-swizzled src (elems)

    f32x4 acc[4][4] = {};

    for (int k0 = 0; k0 < 1024; k0 += 64) {
        __syncthreads();
        #pragma unroll
        for (int i = 0; i < 4; ++i) {
            const int chunk = w * 4 + i;
            const int row = chunk * 8 + chunkR;
            gload16(xb + (size_t)(m0 + row) * 1024 + k0 + srcOff, As + chunk * 1024);
            gload16(Wt + (size_t)(n0 + row) * 1024 + k0 + srcOff, Bs + chunk * 1024);
        }
        __syncthreads();   // compiler drains vmcnt before s_barrier
        #pragma unroll
        for (int kk = 0; kk < 2; ++kk) {
            bf16x8 af[4], bfr[4];
            #pragma unroll
            for (int mf = 0; mf < 4; ++mf) {
                const int row = wm * 64 + mf * 16 + lr;
                af[mf] = *(const bf16x8*)(As + row * 128 +
                          ((kk * 64 + lg * 16) ^ ((row & 7) << 4)));
            }
            #pragma unroll
            for (int nf = 0; nf < 4; ++nf) {
                const int row = wn * 64 + nf * 16 + lr;
                bfr[nf] = *(const bf16x8*)(Bs + row * 128 +
                          ((kk * 64 + lg * 16) ^ ((row & 7) << 4)));
            }
            #pragma unroll
            for (int mf = 0; mf < 4; ++mf)
                #pragma unroll
                for (int nf = 0; nf < 4; ++nf)
                    acc[mf][nf] = __builtin_amdgcn_mfma_f32_16x16x32_bf16(
                        af[mf], bfr[nf], acc[mf][nf], 0, 0, 0);
        }
    }

    // Epilogue: C row m = m0+wm*64+mf*16+lg*4+r, col = n0+wn*64+nf*16+lr
    const float rsign = (lane & 1) ? 1.f : -1.f;
    #pragma unroll
    for (int nf = 0; nf < 4; ++nf) {
        const int col = n0 + wn * 64 + nf * 16 + lr;
        #pragma unroll
        for (int mf = 0; mf < 4; ++mf) {
            const int mrow = m0 + wm * 64 + mf * 16 + lg * 4;
            const int b = mrow >> 11;
            const int t0 = mrow & 2047;
            if (col < 1280) {   // Q or K: RoPE (block-uniform branch)
                const int d = col & 63;
                #pragma unroll
                for (int r = 0; r < 4; ++r) {
                    float val = acc[mf][nf][r];
                    float partner = __shfl_xor(val, 1);
                    const int t = t0 + r;
                    float cs = cosp[t * 64 + d], sn = sinp[t * 64 + d];
                    unsigned short ub = f2bf(val * cs + rsign * partner * sn);
                    if (col < 1024) {
                        const int h = col >> 6;
                        Qw[(((size_t)b * H_ + h) * T_ + t) * 64 + d] = ub;
                    } else {
                        const int kv = (col - 1024) >> 6;
                        // swizzled store: byte = t*128 + (2d ^ ((t&7)<<4))
                        char* krow = (char*)Kw +
                            ((((size_t)b * KV_ + kv) * T_ + t) << 7);
                        *(unsigned short*)(krow + ((2 * d) ^ ((t & 7) << 4))) = ub;
                    }
                }
            } else {            // V: transposed swizzled store, 4 t packed (8B)
                const int cv = col - 1280, kv = cv >> 6, d = cv & 63;
                unsigned short u[4];
                #pragma unroll
                for (int r = 0; r < 4; ++r) u[r] = f2bf(acc[mf][nf][r]);
                char* vrow = (char*)Vtw +
                    ((((size_t)b * KV_ + kv) * 64 + d) * (size_t)T_ * 2);
                *(u16x4*)(vrow + ((2 * t0) ^ ((d & 7) << 4))) = *(u16x4*)u;
            }
        }
    }
}

// ---------------------------------------------------------------------------
// Kernel 2: causal GQA flash attention, bf16 MFMA, f32 accum, bf16 out.
// Double-buffered K/V staging via global_load_lds (pre-swizzled global),
// one barrier per tile; setprio around MFMA clusters.
// ---------------------------------------------------------------------------
__global__ __launch_bounds__(256) void attn_kernel(
    const unsigned short* __restrict__ Qg, const unsigned short* __restrict__ Kg,
    const unsigned short* __restrict__ Vtg, const float* __restrict__ maskp,
    unsigned short* __restrict__ attn_out)
{
    __shared__ __align__(16) unsigned char Kl[2][8192];   // [key][d], swizzled content
    __shared__ __align__(16) unsigned char Vl[2][8192];   // [d][key], swizzled content
    __shared__ __align__(16) unsigned char Pl[4][2048];   // per-wave P, swizzled

    const int tid  = threadIdx.x;
    const int lane = tid & 63;
    const int w    = tid >> 6;
    const int lr   = lane & 15;
    const int lg   = lane >> 4;

    const int bi = blockIdx.x;
    const int qt = 31 - (bi & 31);         // descending: long blocks first
    const int bh = bi >> 5;
    const int h  = bh & 15;
    const int b  = bh >> 4;
    const int kvh = h >> 2;
    const int q0 = qt * 64;

    const unsigned short* Qbase =
        Qg + (((size_t)b * H_ + h) * T_ + q0 + w * 16 + lr) * HD_;
    bf16x8 qf0 = *(const bf16x8*)(Qbase + lg * 8);
    bf16x8 qf1 = *(const bf16x8*)(Qbase + 32 + lg * 8);

    const char* Kb = (const char*)(Kg  + ((size_t)b * KV_ + kvh) * T_ * HD_);
    const char* Vb = (const char*)(Vtg + ((size_t)b * KV_ + kvh) * HD_ * T_);

    // staging coords: wave w covers row-blocks w*2, w*2+1 (8 rows x 128B each)
    const int sr  = lane >> 3;          // 0..7 row within row-block
    const int scb = (lane & 7) * 16;    // byte col

    f32x4 o[4];
    float m[4], lsum[4];
    #pragma unroll
    for (int n = 0; n < 4; ++n) o[n] = (f32x4){0.f, 0.f, 0.f, 0.f};
    #pragma unroll
    for (int r = 0; r < 4; ++r) { m[r] = -1e30f; lsum[r] = 0.f; }

    const int qrow_base = q0 + w * 16 + lg * 4;
    unsigned char* Pw = &Pl[w][0];

    // prologue: stage tile 0 into buffer 0
    #pragma unroll
    for (int i = 0; i < 2; ++i) {
        const int rb  = w * 2 + i;
        const int row = rb * 8 + sr;
        gload16(Kb + (size_t)row * 128 + scb,  &Kl[0][rb * 1024]);
        gload16(Vb + (size_t)row * 4096 + scb, &Vl[0][rb * 1024]);
    }
    __syncthreads();

    for (int kt = 0; kt <= qt; ++kt) {
        const int cur = kt & 1;
        const int k0 = kt * 64;

        if (kt < qt) {                    // stage next tile into other buffer
            const int k0n = k0 + 64;
            #pragma unroll
            for (int i = 0; i < 2; ++i) {
                const int rb  = w * 2 + i;
                const int row = rb * 8 + sr;
                gload16(Kb + (size_t)(k0n + row) * 128 + scb,
                        &Kl[cur ^ 1][rb * 1024]);
                gload16(Vb + (size_t)row * 4096 + 2 * k0n + scb,
                        &Vl[cur ^ 1][rb * 1024]);
            }
        }

        const unsigned char* Kc = &Kl[cur][0];
        const unsigned char* Vc = &Vl[cur][0];

        // QK^T: S[16 q][64 key] per wave
        f32x4 s[4];
        #pragma unroll
        for (int n = 0; n < 4; ++n) s[n] = (f32x4){0.f, 0.f, 0.f, 0.f};
        __builtin_amdgcn_s_setprio(1);
        #pragma unroll
        for (int n = 0; n < 4; ++n) {
            const int key = 16 * n + lr;
            #pragma unroll
            for (int ks = 0; ks < 2; ++ks) {
                bf16x8 kb = *(const bf16x8*)(Kc +
                    ((key * 128 + 64 * ks + lg * 16) ^ ((key & 7) << 4)));
                s[n] = __builtin_amdgcn_mfma_f32_16x16x32_bf16(
                    ks == 0 ? qf0 : qf1, kb, s[n], 0, 0, 0);
            }
        }
        __builtin_amdgcn_s_setprio(0);

        // mask + scale
        #pragma unroll
        for (int n = 0; n < 4; ++n) {
            const int keyg = k0 + 16 * n + lr;
            const float mv = maskp[b * T_ + keyg];
            #pragma unroll
            for (int r = 0; r < 4; ++r) {
                bool ok = (keyg <= qrow_base + r) && (mv > 0.f);
                s[n][r] = ok ? s[n][r] * 0.125f : -1e30f;
            }
        }

        // online softmax (rows split across 16-lane groups: xor 1,2,4,8)
        float p[4][4];
        #pragma unroll
        for (int r = 0; r < 4; ++r) {
            float rmax = fmaxf(fmaxf(s[0][r], s[1][r]), fmaxf(s[2][r], s[3][r]));
            rmax = fmaxf(rmax, __shfl_xor(rmax, 1));
            rmax = fmaxf(rmax, __shfl_xor(rmax, 2));
            rmax = fmaxf(rmax, __shfl_xor(rmax, 4));
            rmax = fmaxf(rmax, __shfl_xor(rmax, 8));
            float mnew  = fmaxf(m[r], rmax);
            float alpha = __expf(m[r] - mnew);
            m[r] = mnew;
            float rsum = 0.f;
            #pragma unroll
            for (int n = 0; n < 4; ++n) {
                float pv = __expf(s[n][r] - mnew);
                p[n][r] = pv;
                rsum += pv;
            }
            rsum += __shfl_xor(rsum, 1);
            rsum += __shfl_xor(rsum, 2);
            rsum += __shfl_xor(rsum, 4);
            rsum += __shfl_xor(rsum, 8);
            lsum[r] = lsum[r] * alpha + rsum;
            #pragma unroll
            for (int n = 0; n < 4; ++n) o[n][r] *= alpha;
        }

        // P -> wave-private LDS (bf16, swizzled), reshape to A-fragment
        #pragma unroll
        for (int n = 0; n < 4; ++n) {
            const int ky2 = (16 * n + lr) * 2;
            #pragma unroll
            for (int r = 0; r < 4; ++r) {
                const int qr = lg * 4 + r;
                *(unsigned short*)(Pw + ((qr * 128 + ky2) ^ ((qr & 7) << 4))) =
                    f2bf(p[n][r]);
            }
        }
        bf16x8 pa0 = *(const bf16x8*)(Pw + ((lr * 128 +      lg * 16) ^ ((lr & 7) << 4)));
        bf16x8 pa1 = *(const bf16x8*)(Pw + ((lr * 128 + 64 + lg * 16) ^ ((lr & 7) << 4)));

        // PV: O[16 q][64 d] += P @ V
        __builtin_amdgcn_s_setprio(1);
        #pragma unroll
        for (int n = 0; n < 4; ++n) {
            const int d = 16 * n + lr;
            #pragma unroll
            for (int ks = 0; ks < 2; ++ks) {
                bf16x8 vb = *(const bf16x8*)(Vc +
                    ((d * 128 + 64 * ks + lg * 16) ^ ((d & 7) << 4)));
                o[n] = __builtin_amdgcn_mfma_f32_16x16x32_bf16(
                    ks == 0 ? pa0 : pa1, vb, o[n], 0, 0, 0);
            }
        }
        __builtin_amdgcn_s_setprio(0);

        __syncthreads();   // drains vmcnt (next tile landed) + syncs buffers
    }

    #pragma unroll
    for (int n = 0; n < 4; ++n)
        #pragma unroll
        for (int r = 0; r < 4; ++r) {
            int q = q0 + w * 16 + lg * 4 + r;
            attn_out[((size_t)b * T_ + q) * DIM_ + h * HD_ + 16 * n + lr] =
                f2bf(o[n][r] / lsum[r]);
        }
}

// ---------------------------------------------------------------------------
// Kernel 3: output projection bf16 MFMA. d_out = attnb @ Wot^T (f32 out)
// ---------------------------------------------------------------------------
__global__ __launch_bounds__(256) void outproj_mfma_kernel(
    const unsigned short* __restrict__ Ab, const unsigned short* __restrict__ Wot,
    float* __restrict__ out)
{
    __shared__ __align__(16) unsigned char As[16384];
    __shared__ __align__(16) unsigned char Bs[16384];

    const int tid = threadIdx.x, lane = tid & 63, w = tid >> 6;
    const int lr = lane & 15, lg = lane >> 4;
    const int wm = w >> 1, wn = w & 1;
    const int bn = blockIdx.x, bm = blockIdx.y;
    const int m0 = bm * 128, n0 = bn * 128;

    const int chunkR = lane >> 3;
    const int srcOff = 8 * ((lane & 7) ^ chunkR);

    f32x4 acc[4][4] = {};

    for (int k0 = 0; k0 < 1024; k0 += 64) {
        __syncthreads();
        #pragma unroll
        for (int i = 0; i < 4; ++i) {
            const int chunk = w * 4 + i;
            const int row = chunk * 8 + chunkR;
            gload16(Ab  + (size_t)(m0 + row) * 1024 + k0 + srcOff, As + chunk * 1024);
            gload16(Wot + (size_t)(n0 + row) * 1024 + k0 + srcOff, Bs + chunk * 1024);
        }
        __syncthreads();
        #pragma unroll
        for (int kk = 0; kk < 2; ++kk) {
            bf16x8 af[4], bfr[4];
            #pragma unroll
            for (int mf = 0; mf < 4; ++mf) {
                const int row = wm * 64 + mf * 16 + lr;
                af[mf] = *(const bf16x8*)(As + row * 128 +
                          ((kk * 64 + lg * 16) ^ ((row & 7) << 4)));
            }
            #pragma unroll
            for (int nf = 0; nf < 4; ++nf) {
                const int row = wn * 64 + nf * 16 + lr;
                bfr[nf] = *(const bf16x8*)(Bs + row * 128 +
                          ((kk * 64 + lg * 16) ^ ((row & 7) << 4)));
            }
            #pragma unroll
            for (int mf = 0; mf < 4; ++mf)
                #pragma unroll
                for (int nf = 0; nf < 4; ++nf)
                    acc[mf][nf] = __builtin_amdgcn_mfma_f32_16x16x32_bf16(
                        af[mf], bfr[nf], acc[mf][nf], 0, 0, 0);
        }
    }

    #pragma unroll
    for (int nf = 0; nf < 4; ++nf) {
        const int col = n0 + wn * 64 + nf * 16 + lr;
        #pragma unroll
        for (int mf = 0; mf < 4; ++mf) {
            const int mrow = m0 + wm * 64 + mf * 16 + lg * 4;
            #pragma unroll
            for (int r = 0; r < 4; ++r)
                out[(size_t)(mrow + r) * 1024 + col] = acc[mf][nf][r];
        }
    }
}

// ---------------------------------------------------------------------------
extern "C" void kernel_launch(void* const* d_in, const int* in_sizes, int n_in,
                              void* d_out, int out_size, void* d_ws, size_t ws_size,
                              hipStream_t stream)
{
    const float* x     = (const float*)d_in[0];
    const float* sinp  = (const float*)d_in[1];
    const float* cosp  = (const float*)d_in[2];
    const float* maskp = (const float*)d_in[3];
    const float* Wq    = (const float*)d_in[4];
    const float* Wk    = (const float*)d_in[5];
    const float* Wv    = (const float*)d_in[6];
    const float* Wo    = (const float*)d_in[7];

    unsigned short* wsb = (unsigned short*)d_ws;
    unsigned short* xb  = wsb + XB_OFF;
    unsigned short* Wt  = wsb + WT_OFF;
    unsigned short* Wot = wsb + WOT_OFF;
    unsigned short* Qw  = wsb + QB_OFF;
    unsigned short* Kw  = wsb + KB_OFF;
    unsigned short* Vtw = wsb + VTB_OFF;
    unsigned short* Ab  = wsb + AB_OFF;
    float* out = (float*)d_out;

    cvt_kernel<<<2048, 256, 0, stream>>>(x, xb);
    wtrans_kernel<<<dim3(16, 16), 256, 0, stream>>>(Wq, Wt, 1024);
    wtrans_kernel<<<dim3(4, 16), 256, 0, stream>>>(Wk, Wt + 1024u * 1024u, 256);
    wtrans_kernel<<<dim3(4, 16), 256, 0, stream>>>(Wv, Wt + 1280u * 1024u, 256);
    wtrans_kernel<<<dim3(16, 16), 256, 0, stream>>>(Wo, Wot, 1024);

    qkv_mfma_kernel<<<dim3(12, 32), 256, 0, stream>>>(xb, Wt, sinp, cosp,
                                                      Qw, Kw, Vtw);
    attn_kernel<<<dim3(B_ * H_ * (T_ / 64)), 256, 0, stream>>>(
        Qw, Kw, Vtw, maskp, Ab);
    outproj_mfma_kernel<<<dim3(8, 32), 256, 0, stream>>>(Ab, Wot, out);
}

// Round 5
// 138.082 us; speedup vs baseline: 1.3761x; 1.3761x over previous
//
#include <hip/hip_runtime.h>
#include <math.h>

typedef __attribute__((ext_vector_type(8))) short bf16x8;
typedef __attribute__((ext_vector_type(4))) float f32x4;
typedef __attribute__((ext_vector_type(4))) unsigned short u16x4;

#define B_    2
#define T_    2048
#define DIM_  1024
#define H_    16
#define KV_   4
#define HD_   64

static __device__ __forceinline__ unsigned short f2bf(float f) {
    union { float f; unsigned int u; } v; v.f = f;
    unsigned int r = v.u + 0x7fff + ((v.u >> 16) & 1);   // RNE
    return (unsigned short)(r >> 16);
}

static __device__ __forceinline__ void gload16(const void* g, void* l) {
    __builtin_amdgcn_global_load_lds(
        (const __attribute__((address_space(1))) unsigned int*)g,
        (__attribute__((address_space(3))) unsigned int*)l, 16, 0, 0);
}

// Workspace (unsigned short elements):
//   xb   bf16 [4096][1024]          off 0
//   Wt   bf16 [1536][1024]          off 4194304   (Wq^T | Wk^T | Wv^T rows)
//   Wot  bf16 [1024][1024]          off 5767168
//   Q    bf16 [B][H][T][64]         off 6815744   (row-major)
//   K    bf16 [B][KV][T][64]        off 11010048  (XOR-swizzled rows: 2d ^ ((t&7)<<4))
//   Vt   bf16 [B][KV][64][T]        off 12058624  (XOR-swizzled: 2t ^ ((d&7)<<4))
//   attnb bf16 [B][T][DIM]          off 13107200
#define XB_OFF   0u
#define WT_OFF   4194304u
#define WOT_OFF  5767168u
#define QB_OFF   6815744u
#define KB_OFF   11010048u
#define VTB_OFF  12058624u
#define AB_OFF   13107200u

// ---------------------------------------------------------------------------
// Pre-pass: f32 -> bf16 convert (8 elems/thread)
// ---------------------------------------------------------------------------
__global__ __launch_bounds__(256) void cvt_kernel(
    const float* __restrict__ in, unsigned short* __restrict__ out)
{
    const size_t i = ((size_t)blockIdx.x * 256 + threadIdx.x) * 8;
    float4 a = *(const float4*)&in[i];
    float4 b = *(const float4*)&in[i + 4];
    unsigned short u[8] = {f2bf(a.x), f2bf(a.y), f2bf(a.z), f2bf(a.w),
                           f2bf(b.x), f2bf(b.y), f2bf(b.z), f2bf(b.w)};
    *(bf16x8*)&out[i] = *(bf16x8*)u;
}

// ---------------------------------------------------------------------------
// Pre-pass: W f32 [1024][N] -> Wt bf16 [N][1024]  (64x64 LDS tile transpose)
// ---------------------------------------------------------------------------
__global__ __launch_bounds__(256) void wtrans_kernel(
    const float* __restrict__ W, unsigned short* __restrict__ Wt, int N)
{
    __shared__ float Ts[64][65];
    const int n0 = blockIdx.x * 64, k0 = blockIdx.y * 64;
    const int tid = threadIdx.x;
    const int r = tid >> 4, c4 = (tid & 15) * 4;
    #pragma unroll
    for (int i = 0; i < 4; ++i) {
        float4 v = *(const float4*)&W[(size_t)(k0 + r + 16 * i) * N + n0 + c4];
        Ts[r + 16 * i][c4 + 0] = v.x; Ts[r + 16 * i][c4 + 1] = v.y;
        Ts[r + 16 * i][c4 + 2] = v.z; Ts[r + 16 * i][c4 + 3] = v.w;
    }
    __syncthreads();
    const int rn = tid >> 3, ck = (tid & 7) * 8;
    #pragma unroll
    for (int i = 0; i < 2; ++i) {
        int n = rn + 32 * i;
        unsigned short u[8];
        #pragma unroll
        for (int e = 0; e < 8; ++e) u[e] = f2bf(Ts[ck + e][n]);
        *(bf16x8*)&Wt[(size_t)(n0 + n) * 1024 + k0 + ck] = *(bf16x8*)u;
    }
}

// ---------------------------------------------------------------------------
// Kernel 1: QKV bf16 MFMA GEMM + RoPE epilogue.
// C[4096][1536] = xb @ Wt^T. 128x128 tile, BK=64, 4 waves of 64x64.
// K and Vt outputs are stored XOR-swizzled so attention can stage them with
// linear global_load_lds.
// ---------------------------------------------------------------------------
__global__ __launch_bounds__(256) void qkv_mfma_kernel(
    const unsigned short* __restrict__ xb, const unsigned short* __restrict__ Wt,
    const float* __restrict__ sinp, const float* __restrict__ cosp,
    unsigned short* __restrict__ Qw, unsigned short* __restrict__ Kw,
    unsigned short* __restrict__ Vtw)
{
    __shared__ __align__(16) unsigned char As[16384];   // [128 m][128B], XOR-swizzled
    __shared__ __align__(16) unsigned char Bs[16384];   // [128 n][128B]

    const int tid = threadIdx.x, lane = tid & 63, w = tid >> 6;
    const int lr = lane & 15, lg = lane >> 4;
    const int wm = w >> 1, wn = w & 1;
    const int bn = blockIdx.x, bm = blockIdx.y;
    const int m0 = bm * 128, n0 = bn * 128;

    const int chunkR = lane >> 3;                    // row within 8-row chunk
    const int srcOff = 8 * ((lane & 7) ^ chunkR);    // inverse-swizzled src (elems)

    f32x4 acc[4][4] = {};

    for (int k0 = 0; k0 < 1024; k0 += 64) {
        __syncthreads();
        #pragma unroll
        for (int i = 0; i < 4; ++i) {
            const int chunk = w * 4 + i;
            const int row = chunk * 8 + chunkR;
            gload16(xb + (size_t)(m0 + row) * 1024 + k0 + srcOff, As + chunk * 1024);
            gload16(Wt + (size_t)(n0 + row) * 1024 + k0 + srcOff, Bs + chunk * 1024);
        }
        __syncthreads();   // compiler drains vmcnt before s_barrier
        #pragma unroll
        for (int kk = 0; kk < 2; ++kk) {
            bf16x8 af[4], bfr[4];
            #pragma unroll
            for (int mf = 0; mf < 4; ++mf) {
                const int row = wm * 64 + mf * 16 + lr;
                af[mf] = *(const bf16x8*)(As + row * 128 +
                          ((kk * 64 + lg * 16) ^ ((row & 7) << 4)));
            }
            #pragma unroll
            for (int nf = 0; nf < 4; ++nf) {
                const int row = wn * 64 + nf * 16 + lr;
                bfr[nf] = *(const bf16x8*)(Bs + row * 128 +
                          ((kk * 64 + lg * 16) ^ ((row & 7) << 4)));
            }
            #pragma unroll
            for (int mf = 0; mf < 4; ++mf)
                #pragma unroll
                for (int nf = 0; nf < 4; ++nf)
                    acc[mf][nf] = __builtin_amdgcn_mfma_f32_16x16x32_bf16(
                        af[mf], bfr[nf], acc[mf][nf], 0, 0, 0);
        }
    }

    // Epilogue: C row m = m0+wm*64+mf*16+lg*4+r, col = n0+wn*64+nf*16+lr
    const float rsign = (lane & 1) ? 1.f : -1.f;
    #pragma unroll
    for (int nf = 0; nf < 4; ++nf) {
        const int col = n0 + wn * 64 + nf * 16 + lr;
        #pragma unroll
        for (int mf = 0; mf < 4; ++mf) {
            const int mrow = m0 + wm * 64 + mf * 16 + lg * 4;
            const int b = mrow >> 11;
            const int t0 = mrow & 2047;
            if (col < 1280) {   // Q or K: RoPE (block-uniform branch)
                const int d = col & 63;
                #pragma unroll
                for (int r = 0; r < 4; ++r) {
                    float val = acc[mf][nf][r];
                    float partner = __shfl_xor(val, 1);
                    const int t = t0 + r;
                    float cs = cosp[t * 64 + d], sn = sinp[t * 64 + d];
                    unsigned short ub = f2bf(val * cs + rsign * partner * sn);
                    if (col < 1024) {
                        const int h = col >> 6;
                        Qw[(((size_t)b * H_ + h) * T_ + t) * 64 + d] = ub;
                    } else {
                        const int kv = (col - 1024) >> 6;
                        // swizzled store: byte = t*128 + (2d ^ ((t&7)<<4))
                        char* krow = (char*)Kw +
                            ((((size_t)b * KV_ + kv) * T_ + t) << 7);
                        *(unsigned short*)(krow + ((2 * d) ^ ((t & 7) << 4))) = ub;
                    }
                }
            } else {            // V: transposed swizzled store, 4 t packed (8B)
                const int cv = col - 1280, kv = cv >> 6, d = cv & 63;
                unsigned short u[4];
                #pragma unroll
                for (int r = 0; r < 4; ++r) u[r] = f2bf(acc[mf][nf][r]);
                char* vrow = (char*)Vtw +
                    ((((size_t)b * KV_ + kv) * 64 + d) * (size_t)T_ * 2);
                *(u16x4*)(vrow + ((2 * t0) ^ ((d & 7) << 4))) = *(u16x4*)u;
            }
        }
    }
}

// ---------------------------------------------------------------------------
// Kernel 2: causal GQA flash attention, bf16 MFMA, transposed-S form.
// mfma(K,Q) -> S^T: col=lane&15=q, rows=keys -> softmax reduction is
// 15 in-reg ops + 2 shuffles; per-lane state m,l scalars.
// PV: O^T = mfma(Vt, P^T). Block = 4 waves x 16 q-rows; two q-tiles
// (qt, 31-qt) per block for uniform work (33 key-tiles each).
// ---------------------------------------------------------------------------
__global__ __launch_bounds__(256) void attn_kernel(
    const unsigned short* __restrict__ Qg, const unsigned short* __restrict__ Kg,
    const unsigned short* __restrict__ Vtg, const float* __restrict__ maskp,
    unsigned short* __restrict__ attn_out)
{
    __shared__ __align__(16) unsigned char Kl[2][8192];   // [key][d], swizzled
    __shared__ __align__(16) unsigned char Vl[2][8192];   // [d][key], swizzled
    __shared__ __align__(16) unsigned char Pl[4][2048];   // per-wave P^T [q][key]

    const int tid  = threadIdx.x;
    const int lane = tid & 63;
    const int w    = tid >> 6;
    const int lr   = lane & 15;
    const int lg   = lane >> 4;

    const int bi = blockIdx.x;
    const int pairIdx = bi & 15;
    const int bh = bi >> 4;
    const int h  = bh & 15;
    const int b  = bh >> 4;
    const int kvh = h >> 2;

    const char* Kb = (const char*)(Kg  + ((size_t)b * KV_ + kvh) * T_ * HD_);
    const char* Vb = (const char*)(Vtg + ((size_t)b * KV_ + kvh) * HD_ * T_);
    const float* mrow = maskp + b * T_;

    const int sr  = lane >> 3;          // staging row within 8-row block
    const int scb = (lane & 7) * 16;    // staging byte col
    unsigned char* Pw = &Pl[w][0];

    for (int pass = 0; pass < 2; ++pass) {
        const int qt = pass ? pairIdx : 31 - pairIdx;   // long tile first
        const int q0 = qt * 64;
        const int qrow = q0 + w * 16 + lr;              // this lane's q row

        // Q fragments for this pass (B-operand: col=lane&15=q, k=d)
        const unsigned short* Qbase =
            Qg + (((size_t)b * H_ + h) * T_ + qrow) * HD_;
        const bf16x8 qf0 = *(const bf16x8*)(Qbase + lg * 8);
        const bf16x8 qf1 = *(const bf16x8*)(Qbase + 32 + lg * 8);

        f32x4 o[4] = {};
        float m = -1e30f, l = 0.f;

        // prologue: stage tile 0 into buffer 0
        #pragma unroll
        for (int i = 0; i < 2; ++i) {
            const int rb  = w * 2 + i;
            const int row = rb * 8 + sr;
            gload16(Kb + (size_t)row * 128 + scb,  &Kl[0][rb * 1024]);
            gload16(Vb + (size_t)row * 4096 + scb, &Vl[0][rb * 1024]);
        }
        __syncthreads();

        for (int kt = 0; kt <= qt; ++kt) {
            const int cur = kt & 1;
            const int k0 = kt * 64;

            if (kt < qt) {                    // stage next tile, other buffer
                const int k0n = k0 + 64;
                #pragma unroll
                for (int i = 0; i < 2; ++i) {
                    const int rb  = w * 2 + i;
                    const int row = rb * 8 + sr;
                    gload16(Kb + (size_t)(k0n + row) * 128 + scb,
                            &Kl[cur ^ 1][rb * 1024]);
                    gload16(Vb + (size_t)row * 4096 + 2 * k0n + scb,
                            &Vl[cur ^ 1][rb * 1024]);
                }
            }

            const unsigned char* Kc = &Kl[cur][0];
            const unsigned char* Vc = &Vl[cur][0];

            // mask values for this lane's 16 keys (float4 per n)
            f32x4 mv[4];
            #pragma unroll
            for (int n = 0; n < 4; ++n)
                mv[n] = *(const f32x4*)&mrow[k0 + 16 * n + 4 * lg];

            // QK^T transposed: s[n][r] = S[key=k0+16n+4lg+r][q=qrow]
            f32x4 s[4] = {};
            __builtin_amdgcn_s_setprio(1);
            #pragma unroll
            for (int n = 0; n < 4; ++n) {
                const int key = 16 * n + lr;
                #pragma unroll
                for (int ks = 0; ks < 2; ++ks) {
                    bf16x8 kb = *(const bf16x8*)(Kc +
                        ((key * 128 + 64 * ks + lg * 16) ^ ((key & 7) << 4)));
                    s[n] = __builtin_amdgcn_mfma_f32_16x16x32_bf16(
                        kb, ks == 0 ? qf0 : qf1, s[n], 0, 0, 0);
                }
            }
            __builtin_amdgcn_s_setprio(0);

            // scale + mask (+ causal on diagonal tile)
            if (kt == qt) {
                #pragma unroll
                for (int n = 0; n < 4; ++n) {
                    #pragma unroll
                    for (int r = 0; r < 4; ++r) {
                        const int keyg = k0 + 16 * n + 4 * lg + r;
                        bool ok = (keyg <= qrow) && (mv[n][r] > 0.f);
                        s[n][r] = ok ? s[n][r] * 0.125f : -1e30f;
                    }
                }
            } else {
                #pragma unroll
                for (int n = 0; n < 4; ++n)
                    #pragma unroll
                    for (int r = 0; r < 4; ++r)
                        s[n][r] = (mv[n][r] > 0.f) ? s[n][r] * 0.125f : -1e30f;
            }

            // online softmax: lane-local over 16 keys + 2 shuffles
            float mx = s[0][0];
            #pragma unroll
            for (int n = 0; n < 4; ++n)
                #pragma unroll
                for (int r = 0; r < 4; ++r)
                    if (n || r) mx = fmaxf(mx, s[n][r]);
            mx = fmaxf(mx, __shfl_xor(mx, 16));
            mx = fmaxf(mx, __shfl_xor(mx, 32));
            const float mnew = fmaxf(m, mx);
            const float alpha = __expf(m - mnew);
            m = mnew;
            float rsum = 0.f;
            #pragma unroll
            for (int n = 0; n < 4; ++n)
                #pragma unroll
                for (int r = 0; r < 4; ++r) {
                    float pv = __expf(s[n][r] - mnew);
                    s[n][r] = pv;
                    rsum += pv;
                }
            rsum += __shfl_xor(rsum, 16);
            rsum += __shfl_xor(rsum, 32);
            l = l * alpha + rsum;
            #pragma unroll
            for (int n = 0; n < 4; ++n) o[n] *= alpha;

            // P^T -> wave-private LDS: row q=lr, 4 consecutive keys per b64
            #pragma unroll
            for (int n = 0; n < 4; ++n) {
                unsigned int w0 = (unsigned int)f2bf(s[n][0]) |
                                  ((unsigned int)f2bf(s[n][1]) << 16);
                unsigned int w1 = (unsigned int)f2bf(s[n][2]) |
                                  ((unsigned int)f2bf(s[n][3]) << 16);
                uint2 wv; wv.x = w0; wv.y = w1;
                *(uint2*)(Pw + ((lr * 128 + 32 * n + 8 * lg) ^ ((lr & 7) << 4))) = wv;
            }
            bf16x8 pa0 = *(const bf16x8*)(Pw + ((lr * 128 +      lg * 16) ^ ((lr & 7) << 4)));
            bf16x8 pa1 = *(const bf16x8*)(Pw + ((lr * 128 + 64 + lg * 16) ^ ((lr & 7) << 4)));

            // PV transposed: o[n][r] = O[q=qrow][d=16n+4lg+r]
            __builtin_amdgcn_s_setprio(1);
            #pragma unroll
            for (int n = 0; n < 4; ++n) {
                const int d = 16 * n + lr;
                #pragma unroll
                for (int ks = 0; ks < 2; ++ks) {
                    bf16x8 vb = *(const bf16x8*)(Vc +
                        ((d * 128 + 64 * ks + lg * 16) ^ ((d & 7) << 4)));
                    o[n] = __builtin_amdgcn_mfma_f32_16x16x32_bf16(
                        vb, ks == 0 ? pa0 : pa1, o[n], 0, 0, 0);
                }
            }
            __builtin_amdgcn_s_setprio(0);

            __syncthreads();   // drains vmcnt (next tile landed) + swap buffers
        }

        // epilogue: lane owns q=qrow, d = 16n+4lg+{0..3}
        const float linv = 1.f / l;
        unsigned short* orow = attn_out + ((size_t)b * T_ + qrow) * DIM_ + h * HD_;
        #pragma unroll
        for (int n = 0; n < 4; ++n) {
            unsigned short u[4];
            #pragma unroll
            for (int r = 0; r < 4; ++r) u[r] = f2bf(o[n][r] * linv);
            *(u16x4*)&orow[16 * n + 4 * lg] = *(u16x4*)u;
        }
        __syncthreads();       // all waves done before pass-1 restages buf 0
    }
}

// ---------------------------------------------------------------------------
// Kernel 3: output projection bf16 MFMA. d_out = attnb @ Wot^T (f32 out)
// ---------------------------------------------------------------------------
__global__ __launch_bounds__(256) void outproj_mfma_kernel(
    const unsigned short* __restrict__ Ab, const unsigned short* __restrict__ Wot,
    float* __restrict__ out)
{
    __shared__ __align__(16) unsigned char As[16384];
    __shared__ __align__(16) unsigned char Bs[16384];

    const int tid = threadIdx.x, lane = tid & 63, w = tid >> 6;
    const int lr = lane & 15, lg = lane >> 4;
    const int wm = w >> 1, wn = w & 1;
    const int bn = blockIdx.x, bm = blockIdx.y;
    const int m0 = bm * 128, n0 = bn * 128;

    const int chunkR = lane >> 3;
    const int srcOff = 8 * ((lane & 7) ^ chunkR);

    f32x4 acc[4][4] = {};

    for (int k0 = 0; k0 < 1024; k0 += 64) {
        __syncthreads();
        #pragma unroll
        for (int i = 0; i < 4; ++i) {
            const int chunk = w * 4 + i;
            const int row = chunk * 8 + chunkR;
            gload16(Ab  + (size_t)(m0 + row) * 1024 + k0 + srcOff, As + chunk * 1024);
            gload16(Wot + (size_t)(n0 + row) * 1024 + k0 + srcOff, Bs + chunk * 1024);
        }
        __syncthreads();
        #pragma unroll
        for (int kk = 0; kk < 2; ++kk) {
            bf16x8 af[4], bfr[4];
            #pragma unroll
            for (int mf = 0; mf < 4; ++mf) {
                const int row = wm * 64 + mf * 16 + lr;
                af[mf] = *(const bf16x8*)(As + row * 128 +
                          ((kk * 64 + lg * 16) ^ ((row & 7) << 4)));
            }
            #pragma unroll
            for (int nf = 0; nf < 4; ++nf) {
                const int row = wn * 64 + nf * 16 + lr;
                bfr[nf] = *(const bf16x8*)(Bs + row * 128 +
                          ((kk * 64 + lg * 16) ^ ((row & 7) << 4)));
            }
            #pragma unroll
            for (int mf = 0; mf < 4; ++mf)
                #pragma unroll
                for (int nf = 0; nf < 4; ++nf)
                    acc[mf][nf] = __builtin_amdgcn_mfma_f32_16x16x32_bf16(
                        af[mf], bfr[nf], acc[mf][nf], 0, 0, 0);
        }
    }

    #pragma unroll
    for (int nf = 0; nf < 4; ++nf) {
        const int col = n0 + wn * 64 + nf * 16 + lr;
        #pragma unroll
        for (int mf = 0; mf < 4; ++mf) {
            const int mrow = m0 + wm * 64 + mf * 16 + lg * 4;
            #pragma unroll
            for (int r = 0; r < 4; ++r)
                out[(size_t)(mrow + r) * 1024 + col] = acc[mf][nf][r];
        }
    }
}

// ---------------------------------------------------------------------------
extern "C" void kernel_launch(void* const* d_in, const int* in_sizes, int n_in,
                              void* d_out, int out_size, void* d_ws, size_t ws_size,
                              hipStream_t stream)
{
    const float* x     = (const float*)d_in[0];
    const float* sinp  = (const float*)d_in[1];
    const float* cosp  = (const float*)d_in[2];
    const float* maskp = (const float*)d_in[3];
    const float* Wq    = (const float*)d_in[4];
    const float* Wk    = (const float*)d_in[5];
    const float* Wv    = (const float*)d_in[6];
    const float* Wo    = (const float*)d_in[7];

    unsigned short* wsb = (unsigned short*)d_ws;
    unsigned short* xb  = wsb + XB_OFF;
    unsigned short* Wt  = wsb + WT_OFF;
    unsigned short* Wot = wsb + WOT_OFF;
    unsigned short* Qw  = wsb + QB_OFF;
    unsigned short* Kw  = wsb + KB_OFF;
    unsigned short* Vtw = wsb + VTB_OFF;
    unsigned short* Ab  = wsb + AB_OFF;
    float* out = (float*)d_out;

    cvt_kernel<<<2048, 256, 0, stream>>>(x, xb);
    wtrans_kernel<<<dim3(16, 16), 256, 0, stream>>>(Wq, Wt, 1024);
    wtrans_kernel<<<dim3(4, 16), 256, 0, stream>>>(Wk, Wt + 1024u * 1024u, 256);
    wtrans_kernel<<<dim3(4, 16), 256, 0, stream>>>(Wv, Wt + 1280u * 1024u, 256);
    wtrans_kernel<<<dim3(16, 16), 256, 0, stream>>>(Wo, Wot, 1024);

    qkv_mfma_kernel<<<dim3(12, 32), 256, 0, stream>>>(xb, Wt, sinp, cosp,
                                                      Qw, Kw, Vtw);
    attn_kernel<<<dim3(B_ * H_ * 16), 256, 0, stream>>>(
        Qw, Kw, Vtw, maskp, Ab);
    outproj_mfma_kernel<<<dim3(8, 32), 256, 0, stream>>>(Ab, Wot, out);
}